// Round 1
// baseline (517.778 us; speedup 1.0000x reference)
//
#include <hip/hip_runtime.h>

// Problem constants
// B=32, DIM=512, C=128, NH=4, HD=32, WS=14, N=196, H_IN=56
#define QSCALE 0.17677669529663687f   // 32^-0.5

// ---------------------------------------------------------------------------
// Kernel 1: grouped 4x4/s4 conv + BN(eval) + ReLU6 -> t[B][196][128]
// block = (c, b); stages the 4 contiguous input channels (12544 floats) in LDS
// ---------------------------------------------------------------------------
__global__ __launch_bounds__(256) void conv_embed_kernel(
    const float* __restrict__ x, const float* __restrict__ cw,
    const float* __restrict__ cb, const float* __restrict__ gam,
    const float* __restrict__ bet, const float* __restrict__ mea,
    const float* __restrict__ var, float* __restrict__ tbuf)
{
  __shared__ __align__(16) float xs[12544];
  __shared__ __align__(16) float wsm[64];
  const int c = blockIdx.x, b = blockIdx.y, tid = threadIdx.x;
  const float4* xb = (const float4*)(x + (b*512 + 4*c)*3136);
  for (int t = tid; t < 3136; t += 256) ((float4*)xs)[t] = xb[t];
  if (tid < 64) wsm[tid] = cw[c*64 + tid];
  __syncthreads();
  if (tid < 196) {
    int oy = tid / 14, ox = tid - (tid/14)*14;
    float acc = cb[c];
#pragma unroll
    for (int i = 0; i < 4; ++i)
#pragma unroll
      for (int kh = 0; kh < 4; ++kh) {
        float4 xv = *(const float4*)&xs[i*3136 + (4*oy+kh)*56 + 4*ox];
        float4 wv = *(const float4*)&wsm[i*16 + kh*4];
        acc += xv.x*wv.x + xv.y*wv.y + xv.z*wv.z + xv.w*wv.w;
      }
    float sc = gam[c] * rsqrtf(var[c] + 1e-5f);
    float v = acc*sc + (bet[c] - mea[c]*sc);
    v = fminf(fmaxf(v, 0.0f), 6.0f);
    tbuf[(b*196 + tid)*128 + c] = v;
  }
}

// ---------------------------------------------------------------------------
// Kernel 2: fold proj into convout:  Wc[512][128] = convout_w @ proj_w,
//           bias_c[512] = convout_w @ proj_b + convout_b
// ---------------------------------------------------------------------------
__global__ __launch_bounds__(256) void make_wc_kernel(
    const float* __restrict__ cow, const float* __restrict__ pw,
    const float* __restrict__ pb, const float* __restrict__ cob,
    float* __restrict__ Wc, float* __restrict__ bias_c)
{
  int idx = blockIdx.x*256 + threadIdx.x;     // 65536 = 512*128
  int oc = idx >> 7, k = idx & 127;
  float acc = 0.f;
  for (int cc = 0; cc < 128; ++cc) acc += cow[oc*128 + cc] * pw[cc*128 + k];
  Wc[idx] = acc;
  if (blockIdx.x < 2) {                       // first 512 threads also do bias
    float a2 = cob[idx];
    for (int cc = 0; cc < 128; ++cc) a2 += cow[idx*128 + cc] * pb[cc];
    bias_c[idx] = a2;
  }
}

// ---------------------------------------------------------------------------
// Shared 64x64 tile GEMM core: C_tile = A[row0..+64][0..128) @ B[col0..+64][0..128)^T
// LDS layout is k-major, stride 68 (16B aligned, bank-conflict-free reads).
// ---------------------------------------------------------------------------
__device__ __forceinline__ void gemm_tile_64x64(
    const float* __restrict__ Ag, const float* __restrict__ Bg,
    int row0, int col0, float* As, float* Bs, float (&acc)[4][4])
{
  const int tid = threadIdx.x;
#pragma unroll
  for (int it = 0; it < 8; ++it) {
    int rr = (it & 3)*16 + (tid & 15);        // row within tile (fast over lanes
    int kq = (it >> 2)*16 + (tid >> 4);       //  -> 2-way-free LDS stores)
    float4 va = *(const float4*)&Ag[(row0+rr)*128 + kq*4];
    As[(4*kq+0)*68 + rr] = va.x;
    As[(4*kq+1)*68 + rr] = va.y;
    As[(4*kq+2)*68 + rr] = va.z;
    As[(4*kq+3)*68 + rr] = va.w;
    float4 vb = *(const float4*)&Bg[(col0+rr)*128 + kq*4];
    Bs[(4*kq+0)*68 + rr] = vb.x;
    Bs[(4*kq+1)*68 + rr] = vb.y;
    Bs[(4*kq+2)*68 + rr] = vb.z;
    Bs[(4*kq+3)*68 + rr] = vb.w;
  }
  __syncthreads();
  const int tx = (tid & 15)*4, ty = (tid >> 4)*4;
#pragma unroll 8
  for (int k = 0; k < 128; ++k) {
    float4 a4 = *(const float4*)&As[k*68 + ty];
    float4 b4 = *(const float4*)&Bs[k*68 + tx];
    float av[4] = {a4.x, a4.y, a4.z, a4.w};
    float bv[4] = {b4.x, b4.y, b4.z, b4.w};
#pragma unroll
    for (int i = 0; i < 4; ++i)
#pragma unroll
      for (int j = 0; j < 4; ++j) acc[i][j] += av[i]*bv[j];
  }
}

// ---------------------------------------------------------------------------
// Kernel 3: qkv = t @ qkv_w^T, scattered to [s][b][h][n][d], q pre-scaled
// ---------------------------------------------------------------------------
__global__ __launch_bounds__(256) void gemm_qkv_kernel(
    const float* __restrict__ t, const float* __restrict__ qkv_w,
    float* __restrict__ qkv)
{
  __shared__ __align__(16) float As[128*68];
  __shared__ __align__(16) float Bs[128*68];
  float acc[4][4] = {};
  gemm_tile_64x64(t, qkv_w, blockIdx.y*64, blockIdx.x*64, As, Bs, acc);
  const int tid = threadIdx.x;
  const int tx = (tid & 15)*4, ty = (tid >> 4)*4;
#pragma unroll
  for (int i = 0; i < 4; ++i) {
    int row = blockIdx.y*64 + ty + i;
    int bb = row / 196, nn = row - bb*196;
#pragma unroll
    for (int j = 0; j < 4; ++j) {
      int col = blockIdx.x*64 + tx + j;
      int s3 = col >> 7, rr = col & 127;
      int hh = rr >> 5, dd = rr & 31;
      float v = acc[i][j];
      if (s3 == 0) v *= QSCALE;
      qkv[(((s3*32 + bb)*4 + hh)*196 + nn)*32 + dd] = v;
    }
  }
}

// ---------------------------------------------------------------------------
// Kernel 4: windowed attention w/ relative position bias.
// block = (half, h, b): 98 q-rows; K/V/q/rpb staged in LDS; wave-per-4-rows.
// ---------------------------------------------------------------------------
__global__ __launch_bounds__(256) void attn_kernel(
    const float* __restrict__ qkv, const float* __restrict__ rpb,
    float* __restrict__ o)
{
  __shared__ __align__(16) float k_lds[256*36];   // padded rows: it=3 reads m<256
  __shared__ __align__(16) float v_lds[196*36];
  __shared__ __align__(16) float q_lds[100*32];   // 2 pad rows for last group
  __shared__ float rpb_lds[732];
  __shared__ float p_lds[16*200];                 // [wave][row-in-group][m]
  const int half = blockIdx.x, h = blockIdx.y, b = blockIdx.z;
  const int tid = threadIdx.x;
  const int n0 = half*98;
  const float* qg = qkv + ((0*32 + b)*4 + h)*6272 + n0*32;
  const float* kg = qkv + ((1*32 + b)*4 + h)*6272;
  const float* vg = qkv + ((2*32 + b)*4 + h)*6272;
  for (int t4 = tid; t4 < 1568; t4 += 256) {      // 196*32/4
    float4 kv = ((const float4*)kg)[t4];
    float4 vv = ((const float4*)vg)[t4];
    int m = t4 >> 3, d = (t4 & 7)*4;
    float* kp = &k_lds[m*36 + d];
    kp[0]=kv.x; kp[1]=kv.y; kp[2]=kv.z; kp[3]=kv.w;
    float* vp = &v_lds[m*36 + d];
    vp[0]=vv.x; vp[1]=vv.y; vp[2]=vv.z; vp[3]=vv.w;
  }
  for (int t4 = tid; t4 < 784; t4 += 256)
    ((float4*)q_lds)[t4] = ((const float4*)qg)[t4];
  for (int t = tid; t < 729; t += 256) rpb_lds[t] = rpb[t*4 + h];
  __syncthreads();
  const int l = tid & 63, w = tid >> 6;
  const int mg = l >> 3, d4 = l & 7;
  for (int g = w; g < 25; g += 4) {
    const int rcnt = (g == 24) ? 2 : 4;
    float s[4][4];
#pragma unroll
    for (int r = 0; r < 4; ++r)
#pragma unroll
      for (int it = 0; it < 4; ++it) s[r][it] = 0.f;
    // ---- QK^T: lane covers m = it*64+l; 4 rows share k reads
#pragma unroll
    for (int d8 = 0; d8 < 8; ++d8) {
      float4 q4[4];
#pragma unroll
      for (int r = 0; r < 4; ++r)
        q4[r] = *(const float4*)&q_lds[(g*4+r)*32 + d8*4];
#pragma unroll
      for (int it = 0; it < 4; ++it) {
        int m = it*64 + l;                        // garbage for m>=196, masked later
        float4 k4 = *(const float4*)&k_lds[m*36 + d8*4];
#pragma unroll
        for (int r = 0; r < 4; ++r)
          s[r][it] += q4[r].x*k4.x + q4[r].y*k4.y + q4[r].z*k4.z + q4[r].w*k4.w;
      }
    }
    // ---- + relative position bias, row max
    float mx[4] = {-1e30f, -1e30f, -1e30f, -1e30f};
    int yn[4], xn[4];
#pragma unroll
    for (int r = 0; r < 4; ++r) {
      int n = n0 + g*4 + r; if (n > 195) n = 195;
      yn[r] = n / 14; xn[r] = n - yn[r]*14;
    }
#pragma unroll
    for (int it = 0; it < 4; ++it) {
      int m = it*64 + l;
      if (m < 196) {
        int ym = m / 14, xm = m - ym*14;
#pragma unroll
        for (int r = 0; r < 4; ++r) {
          s[r][it] += rpb_lds[(yn[r]-ym+13)*27 + (xn[r]-xm+13)];
          mx[r] = fmaxf(mx[r], s[r][it]);
        }
      }
    }
#pragma unroll
    for (int off = 32; off > 0; off >>= 1)
#pragma unroll
      for (int r = 0; r < 4; ++r)
        mx[r] = fmaxf(mx[r], __shfl_xor(mx[r], off));
    // ---- softmax numerator, row sum, stash p in per-wave LDS
    float sum[4] = {0.f, 0.f, 0.f, 0.f};
#pragma unroll
    for (int it = 0; it < 4; ++it) {
      int m = it*64 + l;
      if (m < 196) {
#pragma unroll
        for (int r = 0; r < 4; ++r) {
          float p = __expf(s[r][it] - mx[r]);
          sum[r] += p;
          p_lds[(w*4+r)*200 + m] = p;
        }
      }
    }
#pragma unroll
    for (int off = 32; off > 0; off >>= 1)
#pragma unroll
      for (int r = 0; r < 4; ++r)
        sum[r] += __shfl_xor(sum[r], off);
    // ---- P@V: lane = (mg, d4); 8 m-groups x 8 d-quads
    float4 acc[4];
#pragma unroll
    for (int r = 0; r < 4; ++r) acc[r] = make_float4(0.f, 0.f, 0.f, 0.f);
    for (int t = 0; t < 25; ++t) {
      int m = t*8 + mg;
      if (m < 196) {
        float4 v4 = *(const float4*)&v_lds[m*36 + d4*4];
#pragma unroll
        for (int r = 0; r < 4; ++r) {
          float p = p_lds[(w*4+r)*200 + m];
          acc[r].x += p*v4.x; acc[r].y += p*v4.y;
          acc[r].z += p*v4.z; acc[r].w += p*v4.w;
        }
      }
    }
#pragma unroll
    for (int off = 8; off < 64; off <<= 1)
#pragma unroll
      for (int r = 0; r < 4; ++r) {
        acc[r].x += __shfl_xor(acc[r].x, off);
        acc[r].y += __shfl_xor(acc[r].y, off);
        acc[r].z += __shfl_xor(acc[r].z, off);
        acc[r].w += __shfl_xor(acc[r].w, off);
      }
    if (mg == 0) {
      for (int r = 0; r < rcnt; ++r) {
        int n = n0 + g*4 + r;
        float iv = 1.f / sum[r];
        float4 ov = make_float4(acc[r].x*iv, acc[r].y*iv, acc[r].z*iv, acc[r].w*iv);
        *((float4*)&o[(b*196 + n)*128 + h*32 + d4*4]) = ov;
      }
    }
  }
}

// ---------------------------------------------------------------------------
// Kernel 5: fused proj+convout:  co[b][oc][n] = Wc[oc] . o[b][n] + bias_c[oc]
// ---------------------------------------------------------------------------
__global__ __launch_bounds__(256) void gemm_out_kernel(
    const float* __restrict__ obuf, const float* __restrict__ Wc,
    const float* __restrict__ bias_c, float* __restrict__ co)
{
  __shared__ __align__(16) float As[128*68];
  __shared__ __align__(16) float Bs[128*68];
  float acc[4][4] = {};
  gemm_tile_64x64(obuf, Wc, blockIdx.y*64, blockIdx.x*64, As, Bs, acc);
  const int tid = threadIdx.x;
  const int tx = (tid & 15)*4, ty = (tid >> 4)*4;
#pragma unroll
  for (int i = 0; i < 4; ++i) {
    int row = blockIdx.y*64 + ty + i;
    int bb = row / 196, nn = row - bb*196;
#pragma unroll
    for (int j = 0; j < 4; ++j) {
      int col = blockIdx.x*64 + tx + j;
      co[(bb*512 + col)*196 + nn] = acc[i][j] + bias_c[col];
    }
  }
}

// ---------------------------------------------------------------------------
// Kernel 6: bilinear x4 upsample (align_corners) 14x14 -> 56x56, float4 stores
// block = (cg of 8 channels, b)
// ---------------------------------------------------------------------------
__global__ __launch_bounds__(256) void upsample_kernel(
    const float* __restrict__ co, float* __restrict__ out)
{
  __shared__ float cs[1568];
  __shared__ int lo_s[56];
  __shared__ float w_s[56];
  const int cg = blockIdx.x, b = blockIdx.y, tid = threadIdx.x;
  const float* cbase = co + (b*512 + cg*8)*196;
  for (int t = tid; t < 1568; t += 256) cs[t] = cbase[t];
  if (tid < 56) {
    double s = (double)(tid*13) / 55.0;   // matches numpy double arithmetic
    int lo = (int)s;
    lo_s[tid] = lo;
    w_s[tid] = (float)(s - lo);
  }
  __syncthreads();
  float* obase = out + (b*512 + cg*8)*3136;
  for (int t4 = tid; t4 < 6272; t4 += 256) {       // 8*3136/4
    int ch = t4 / 784;
    int rem = t4 - ch*784;
    int i2 = rem / 14;
    int j4 = (rem - i2*14)*4;
    int li = lo_s[i2]; float wi = w_s[i2];
    int hi = (li+1 < 13) ? li+1 : 13;
    const float* p0 = cs + ch*196 + li*14;
    const float* p1 = cs + ch*196 + hi*14;
    float4 ov;
    float* ovp = (float*)&ov;
#pragma unroll
    for (int jj = 0; jj < 4; ++jj) {
      int j2 = j4 + jj;
      int lj = lo_s[j2]; float wj = w_s[j2];
      int hj = (lj+1 < 13) ? lj+1 : 13;
      float top = p0[lj]*(1.f-wj) + p0[hj]*wj;
      float bot = p1[lj]*(1.f-wj) + p1[hj]*wj;
      ovp[jj] = top*(1.f-wi) + bot*wi;
    }
    ((float4*)obase)[t4] = ov;
  }
}

// ---------------------------------------------------------------------------
extern "C" void kernel_launch(void* const* d_in, const int* in_sizes, int n_in,
                              void* d_out, int out_size, void* d_ws, size_t ws_size,
                              hipStream_t stream)
{
  const float* x         = (const float*)d_in[0];
  const float* conv_w    = (const float*)d_in[1];
  const float* conv_b    = (const float*)d_in[2];
  const float* bn_gamma  = (const float*)d_in[3];
  const float* bn_beta   = (const float*)d_in[4];
  const float* bn_mean   = (const float*)d_in[5];
  const float* bn_var    = (const float*)d_in[6];
  const float* qkv_w     = (const float*)d_in[7];
  // d_in[8] = proj_w, d_in[9] = proj_b  (folded into Wc)
  const float* proj_w    = (const float*)d_in[8];
  const float* proj_b    = (const float*)d_in[9];
  const float* rpb       = (const float*)d_in[10];
  const float* convout_w = (const float*)d_in[11];
  const float* convout_b = (const float*)d_in[12];
  float* out = (float*)d_out;
  float* ws  = (float*)d_ws;

  // workspace layout (floats); total 7,291,392 floats = 27.8 MB
  float* tbuf   = ws;                // 802816   [B,196,128]
  float* qkvb   = ws + 802816;       // 2408448  [3,B,4,196,32]
  float* obuf   = ws + 3211264;      // 802816   [B,196,128]
  float* Wc     = ws + 4014080;      // 65536    [512,128]
  float* bias_c = ws + 4079616;      // 512
  float* co     = ws + 4080128;      // 3211264  [B,512,196]

  conv_embed_kernel<<<dim3(128, 32), 256, 0, stream>>>(
      x, conv_w, conv_b, bn_gamma, bn_beta, bn_mean, bn_var, tbuf);
  make_wc_kernel<<<dim3(256), 256, 0, stream>>>(
      convout_w, proj_w, proj_b, convout_b, Wc, bias_c);
  gemm_qkv_kernel<<<dim3(6, 98), 256, 0, stream>>>(tbuf, qkv_w, qkvb);
  attn_kernel<<<dim3(2, 4, 32), 256, 0, stream>>>(qkvb, rpb, obuf);
  gemm_out_kernel<<<dim3(8, 98), 256, 0, stream>>>(obuf, Wc, bias_c, co);
  upsample_kernel<<<dim3(64, 32), 256, 0, stream>>>(co, out);
}

// Round 2
// 503.208 us; speedup vs baseline: 1.0290x; 1.0290x over previous
//
#include <hip/hip_runtime.h>

// Problem constants: B=32, DIM=512, C=128, NH=4, HD=32, WS=14, N=196, H_IN=56
#define QSCALE 0.17677669529663687f   // 32^-0.5

// ---------------------------------------------------------------------------
// Kernel 1: grouped 4x4/s4 conv + BN(eval) + ReLU6 -> t[B][196][128]
// ---------------------------------------------------------------------------
__global__ __launch_bounds__(256) void conv_embed_kernel(
    const float* __restrict__ x, const float* __restrict__ cw,
    const float* __restrict__ cb, const float* __restrict__ gam,
    const float* __restrict__ bet, const float* __restrict__ mea,
    const float* __restrict__ var, float* __restrict__ tbuf)
{
  __shared__ __align__(16) float xs[12544];
  __shared__ __align__(16) float wsm[64];
  const int c = blockIdx.x, b = blockIdx.y, tid = threadIdx.x;
  const float4* xb = (const float4*)(x + (b*512 + 4*c)*3136);
  for (int t = tid; t < 3136; t += 256) ((float4*)xs)[t] = xb[t];
  if (tid < 64) wsm[tid] = cw[c*64 + tid];
  __syncthreads();
  if (tid < 196) {
    int oy = tid / 14, ox = tid - (tid/14)*14;
    float acc = cb[c];
#pragma unroll
    for (int i = 0; i < 4; ++i)
#pragma unroll
      for (int kh = 0; kh < 4; ++kh) {
        float4 xv = *(const float4*)&xs[i*3136 + (4*oy+kh)*56 + 4*ox];
        float4 wv = *(const float4*)&wsm[i*16 + kh*4];
        acc += xv.x*wv.x + xv.y*wv.y + xv.z*wv.z + xv.w*wv.w;
      }
    float sc = gam[c] * rsqrtf(var[c] + 1e-5f);
    float v = acc*sc + (bet[c] - mea[c]*sc);
    v = fminf(fmaxf(v, 0.0f), 6.0f);
    tbuf[(b*196 + tid)*128 + c] = v;
  }
}

// ---------------------------------------------------------------------------
// Kernel 2: fold proj into convout:  Wc[512][128] = convout_w @ proj_w,
//           bias_c[512] = convout_w @ proj_b + convout_b
// ---------------------------------------------------------------------------
__global__ __launch_bounds__(256) void make_wc_kernel(
    const float* __restrict__ cow, const float* __restrict__ pw,
    const float* __restrict__ pb, const float* __restrict__ cob,
    float* __restrict__ Wc, float* __restrict__ bias_c)
{
  int idx = blockIdx.x*256 + threadIdx.x;     // 65536 = 512*128
  int oc = idx >> 7, k = idx & 127;
  float acc = 0.f;
  for (int cc = 0; cc < 128; ++cc) acc += cow[oc*128 + cc] * pw[cc*128 + k];
  Wc[idx] = acc;
  if (blockIdx.x < 2) {                       // first 512 threads also do bias
    float a2 = cob[idx];
    for (int cc = 0; cc < 128; ++cc) a2 += cow[idx*128 + cc] * pb[cc];
    bias_c[idx] = a2;
  }
}

// ---------------------------------------------------------------------------
// Shared 64x64 tile GEMM core (K=128): k-major LDS, stride 68
// ---------------------------------------------------------------------------
__device__ __forceinline__ void gemm_tile_64x64(
    const float* __restrict__ Ag, const float* __restrict__ Bg,
    int row0, int col0, float* As, float* Bs, float (&acc)[4][4])
{
  const int tid = threadIdx.x;
#pragma unroll
  for (int it = 0; it < 8; ++it) {
    int rr = (it & 3)*16 + (tid & 15);
    int kq = (it >> 2)*16 + (tid >> 4);
    float4 va = *(const float4*)&Ag[(row0+rr)*128 + kq*4];
    As[(4*kq+0)*68 + rr] = va.x;
    As[(4*kq+1)*68 + rr] = va.y;
    As[(4*kq+2)*68 + rr] = va.z;
    As[(4*kq+3)*68 + rr] = va.w;
    float4 vb = *(const float4*)&Bg[(col0+rr)*128 + kq*4];
    Bs[(4*kq+0)*68 + rr] = vb.x;
    Bs[(4*kq+1)*68 + rr] = vb.y;
    Bs[(4*kq+2)*68 + rr] = vb.z;
    Bs[(4*kq+3)*68 + rr] = vb.w;
  }
  __syncthreads();
  const int tx = (tid & 15)*4, ty = (tid >> 4)*4;
#pragma unroll 8
  for (int k = 0; k < 128; ++k) {
    float4 a4 = *(const float4*)&As[k*68 + ty];
    float4 b4 = *(const float4*)&Bs[k*68 + tx];
    float av[4] = {a4.x, a4.y, a4.z, a4.w};
    float bv[4] = {b4.x, b4.y, b4.z, b4.w};
#pragma unroll
    for (int i = 0; i < 4; ++i)
#pragma unroll
      for (int j = 0; j < 4; ++j) acc[i][j] += av[i]*bv[j];
  }
}

// ---------------------------------------------------------------------------
// Kernel 3: qkv = t @ qkv_w^T, scattered to [s][b][h][n][d], q pre-scaled
// ---------------------------------------------------------------------------
__global__ __launch_bounds__(256) void gemm_qkv_kernel(
    const float* __restrict__ t, const float* __restrict__ qkv_w,
    float* __restrict__ qkv)
{
  __shared__ __align__(16) float As[128*68];
  __shared__ __align__(16) float Bs[128*68];
  float acc[4][4] = {};
  gemm_tile_64x64(t, qkv_w, blockIdx.y*64, blockIdx.x*64, As, Bs, acc);
  const int tid = threadIdx.x;
  const int tx = (tid & 15)*4, ty = (tid >> 4)*4;
  const int col0 = blockIdx.x*64 + tx;        // multiple of 4, quad within one 32-blk
  const int s3 = col0 >> 7, rr = col0 & 127;
  const int hh = rr >> 5, dd = rr & 31;
  const float qs = (s3 == 0) ? QSCALE : 1.0f;
#pragma unroll
  for (int i = 0; i < 4; ++i) {
    int row = blockIdx.y*64 + ty + i;
    int bb = row / 196, nn = row - bb*196;
    float4 v;
    v.x = acc[i][0]*qs; v.y = acc[i][1]*qs; v.z = acc[i][2]*qs; v.w = acc[i][3]*qs;
    *(float4*)&qkv[(((s3*32 + bb)*4 + hh)*196 + nn)*32 + dd] = v;
  }
}

// ---------------------------------------------------------------------------
// Kernel 4: St[b][h][m][n(pad 200)] = k_m . q_n + bias(n,m)   (S transposed)
// 64x64 tiles over (m,n), K=32. 2048 blocks, ~20 KB LDS -> high occupancy.
// ---------------------------------------------------------------------------
__global__ __launch_bounds__(256) void score_kernel(
    const float* __restrict__ qkv, const float* __restrict__ rpb,
    float* __restrict__ St)
{
  __shared__ __align__(16) float Ks[32*68];
  __shared__ __align__(16) float Qs[32*68];
  __shared__ float rpb_lds[729];
  const int tile = blockIdx.x, h = blockIdx.y, b = blockIdx.z;
  const int tm = (tile >> 2)*64, tn = (tile & 3)*64;
  const int tid = threadIdx.x;
  const float* qg = qkv + (b*4 + h)*6272;          // q[196][32]
  const float* kg = qkv + ((32 + b)*4 + h)*6272;   // k[196][32]
#pragma unroll
  for (int it = 0; it < 2; ++it) {
    int rr = (tid & 31) + it*32;                   // 0..63
    int kq = tid >> 5;                             // 0..7
    int rk = tm + rr; if (rk > 195) rk = 195;
    float4 va = *(const float4*)&kg[rk*32 + kq*4];
    Ks[(4*kq+0)*68+rr] = va.x; Ks[(4*kq+1)*68+rr] = va.y;
    Ks[(4*kq+2)*68+rr] = va.z; Ks[(4*kq+3)*68+rr] = va.w;
    int rq = tn + rr; if (rq > 195) rq = 195;
    float4 vb = *(const float4*)&qg[rq*32 + kq*4];
    Qs[(4*kq+0)*68+rr] = vb.x; Qs[(4*kq+1)*68+rr] = vb.y;
    Qs[(4*kq+2)*68+rr] = vb.z; Qs[(4*kq+3)*68+rr] = vb.w;
  }
  for (int t = tid; t < 729; t += 256) rpb_lds[t] = rpb[t*4 + h];
  __syncthreads();
  const int tx = (tid & 15)*4, ty = (tid >> 4)*4;
  float acc[4][4] = {};
#pragma unroll 8
  for (int k = 0; k < 32; ++k) {
    float4 a4 = *(const float4*)&Ks[k*68 + ty];
    float4 b4 = *(const float4*)&Qs[k*68 + tx];
    float av[4] = {a4.x, a4.y, a4.z, a4.w};
    float bv[4] = {b4.x, b4.y, b4.z, b4.w};
#pragma unroll
    for (int i = 0; i < 4; ++i)
#pragma unroll
      for (int j = 0; j < 4; ++j) acc[i][j] += av[i]*bv[j];
  }
  // epilogue: add rel-pos bias, store to St[m][n]
  int ym[4], xm[4], yn[4], xn[4];
#pragma unroll
  for (int i = 0; i < 4; ++i) {
    int m = tm + ty + i; if (m > 195) m = 0;
    ym[i] = m / 14; xm[i] = m - ym[i]*14;
  }
#pragma unroll
  for (int j = 0; j < 4; ++j) {
    int n = tn + tx + j; if (n > 195) n = 0;
    yn[j] = n / 14; xn[j] = n - yn[j]*14;
  }
  float* stb = St + ((b*4 + h)*196)*200;
  const bool nfull = (tn + tx + 3 < 196);
#pragma unroll
  for (int i = 0; i < 4; ++i) {
    int m = tm + ty + i;
    if (m >= 196) continue;
    float sv[4];
#pragma unroll
    for (int j = 0; j < 4; ++j)
      sv[j] = acc[i][j] + rpb_lds[(yn[j]-ym[i]+13)*27 + (xn[j]-xm[i]+13)];
    if (nfull) {
      float4 v4; v4.x = sv[0]; v4.y = sv[1]; v4.z = sv[2]; v4.w = sv[3];
      *(float4*)&stb[m*200 + tn + tx] = v4;
    } else {
#pragma unroll
      for (int j = 0; j < 4; ++j)
        if (tn + tx + j < 196) stb[m*200 + tn + tx + j] = sv[j];
    }
  }
}

// ---------------------------------------------------------------------------
// Kernel 5: softmax + PV. One q-row per lane; V broadcast from LDS.
// grid (4,4,32) x 64 threads: rows q4*49..q4*49+48.
// ---------------------------------------------------------------------------
__global__ __launch_bounds__(64) void softmax_pv_kernel(
    const float* __restrict__ qkv, const float* __restrict__ St,
    float* __restrict__ o)
{
  __shared__ __align__(16) float v_lds[196*32];
  const int q4 = blockIdx.x, h = blockIdx.y, b = blockIdx.z;
  const int tid = threadIdx.x;
  const float4* vg = (const float4*)(qkv + ((64 + b)*4 + h)*6272);
  for (int t = tid; t < 1568; t += 64) ((float4*)v_lds)[t] = vg[t];
  __syncthreads();
  const int row = q4*49 + tid;
  const bool act = (tid < 49);
  const int rowc = act ? row : q4*49;
  const float* sp = St + ((b*4 + h)*196)*200 + rowc;
  // pass 1: row max (196 = 49*4)
  float mx = -1e30f;
  for (int m = 0; m < 196; m += 4) {
    float s0 = sp[(m+0)*200], s1 = sp[(m+1)*200];
    float s2 = sp[(m+2)*200], s3 = sp[(m+3)*200];
    mx = fmaxf(mx, fmaxf(fmaxf(s0, s1), fmaxf(s2, s3)));
  }
  // pass 2: exp, sum, accumulate O
  float4 oa[8];
#pragma unroll
  for (int d = 0; d < 8; ++d) oa[d] = make_float4(0.f, 0.f, 0.f, 0.f);
  float sum = 0.f;
#pragma unroll 2
  for (int m = 0; m < 196; ++m) {
    float e = __expf(sp[m*200] - mx);
    sum += e;
    const float4* vr = (const float4*)&v_lds[m*32];
#pragma unroll
    for (int d = 0; d < 8; ++d) {
      float4 v4 = vr[d];
      oa[d].x += e*v4.x; oa[d].y += e*v4.y;
      oa[d].z += e*v4.z; oa[d].w += e*v4.w;
    }
  }
  if (act) {
    float inv = 1.f / sum;
    float4* op = (float4*)&o[(b*196 + row)*128 + h*32];
#pragma unroll
    for (int d = 0; d < 8; ++d) {
      float4 v4;
      v4.x = oa[d].x*inv; v4.y = oa[d].y*inv;
      v4.z = oa[d].z*inv; v4.w = oa[d].w*inv;
      op[d] = v4;
    }
  }
}

// ---------------------------------------------------------------------------
// Kernel 6: fused proj+convout:  co[b][oc][n] = Wc[oc] . o[b][n] + bias_c[oc]
// ---------------------------------------------------------------------------
__global__ __launch_bounds__(256) void gemm_out_kernel(
    const float* __restrict__ obuf, const float* __restrict__ Wc,
    const float* __restrict__ bias_c, float* __restrict__ co)
{
  __shared__ __align__(16) float As[128*68];
  __shared__ __align__(16) float Bs[128*68];
  float acc[4][4] = {};
  gemm_tile_64x64(obuf, Wc, blockIdx.y*64, blockIdx.x*64, As, Bs, acc);
  const int tid = threadIdx.x;
  const int tx = (tid & 15)*4, ty = (tid >> 4)*4;
  const int row0 = blockIdx.y*64 + ty;        // multiple of 4; 196%4==0 -> same bb
  const int bb = row0 / 196, nn0 = row0 - bb*196;
#pragma unroll
  for (int j = 0; j < 4; ++j) {
    int col = blockIdx.x*64 + tx + j;
    float bc = bias_c[col];
    float4 v;
    v.x = acc[0][j] + bc; v.y = acc[1][j] + bc;
    v.z = acc[2][j] + bc; v.w = acc[3][j] + bc;
    *(float4*)&co[(bb*512 + col)*196 + nn0] = v;
  }
}

// ---------------------------------------------------------------------------
// Kernel 7: bilinear x4 upsample (align_corners) 14x14 -> 56x56
// ---------------------------------------------------------------------------
__global__ __launch_bounds__(256) void upsample_kernel(
    const float* __restrict__ co, float* __restrict__ out)
{
  __shared__ float cs[1568];
  __shared__ int lo_s[56];
  __shared__ float w_s[56];
  const int cg = blockIdx.x, b = blockIdx.y, tid = threadIdx.x;
  const float* cbase = co + (b*512 + cg*8)*196;
  for (int t = tid; t < 1568; t += 256) cs[t] = cbase[t];
  if (tid < 56) {
    double s = (double)(tid*13) / 55.0;
    int lo = (int)s;
    lo_s[tid] = lo;
    w_s[tid] = (float)(s - lo);
  }
  __syncthreads();
  float* obase = out + (b*512 + cg*8)*3136;
  for (int t4 = tid; t4 < 6272; t4 += 256) {
    int ch = t4 / 784;
    int rem = t4 - ch*784;
    int i2 = rem / 14;
    int j4 = (rem - i2*14)*4;
    int li = lo_s[i2]; float wi = w_s[i2];
    int hi = (li+1 < 13) ? li+1 : 13;
    const float* p0 = cs + ch*196 + li*14;
    const float* p1 = cs + ch*196 + hi*14;
    float4 ov;
    float* ovp = (float*)&ov;
#pragma unroll
    for (int jj = 0; jj < 4; ++jj) {
      int j2 = j4 + jj;
      int lj = lo_s[j2]; float wj = w_s[j2];
      int hj = (lj+1 < 13) ? lj+1 : 13;
      float top = p0[lj]*(1.f-wj) + p0[hj]*wj;
      float bot = p1[lj]*(1.f-wj) + p1[hj]*wj;
      ovp[jj] = top*(1.f-wi) + bot*wi;
    }
    ((float4*)obase)[t4] = ov;
  }
}

// ---------------------------------------------------------------------------
extern "C" void kernel_launch(void* const* d_in, const int* in_sizes, int n_in,
                              void* d_out, int out_size, void* d_ws, size_t ws_size,
                              hipStream_t stream)
{
  const float* x         = (const float*)d_in[0];
  const float* conv_w    = (const float*)d_in[1];
  const float* conv_b    = (const float*)d_in[2];
  const float* bn_gamma  = (const float*)d_in[3];
  const float* bn_beta   = (const float*)d_in[4];
  const float* bn_mean   = (const float*)d_in[5];
  const float* bn_var    = (const float*)d_in[6];
  const float* qkv_w     = (const float*)d_in[7];
  const float* proj_w    = (const float*)d_in[8];
  const float* proj_b    = (const float*)d_in[9];
  const float* rpb       = (const float*)d_in[10];
  const float* convout_w = (const float*)d_in[11];
  const float* convout_b = (const float*)d_in[12];
  float* out = (float*)d_out;
  float* ws  = (float*)d_ws;

  // workspace layout (floats); total 9,097,728 = 34.7 MB
  float* tbuf   = ws;                // 802816   [B,196,128]
  float* qkvb   = ws + 802816;       // 2408448  [3,B,4,196,32]
  float* obuf   = ws + 3211264;      // 802816   [B,196,128]
  float* Wc     = ws + 4014080;      // 65536    [512,128]
  float* bias_c = ws + 4079616;      // 512
  float* St     = ws + 4080128;      // 5017600  [B,4,196,200]  (aliases co)
  float* co     = ws + 4080128;      // 3211264  [B,512,196]  -- used after St dead

  conv_embed_kernel<<<dim3(128, 32), 256, 0, stream>>>(
      x, conv_w, conv_b, bn_gamma, bn_beta, bn_mean, bn_var, tbuf);
  make_wc_kernel<<<dim3(256), 256, 0, stream>>>(
      convout_w, proj_w, proj_b, convout_b, Wc, bias_c);
  gemm_qkv_kernel<<<dim3(6, 98), 256, 0, stream>>>(tbuf, qkv_w, qkvb);
  score_kernel<<<dim3(16, 4, 32), 256, 0, stream>>>(qkvb, rpb, St);
  softmax_pv_kernel<<<dim3(4, 4, 32), 64, 0, stream>>>(qkvb, St, obuf);
  gemm_out_kernel<<<dim3(8, 98), 256, 0, stream>>>(obuf, Wc, bias_c, co);
  upsample_kernel<<<dim3(64, 32), 256, 0, stream>>>(co, out);
}